// Round 3
// baseline (13877.036 us; speedup 1.0000x reference)
//
#include <hip/hip_runtime.h>

// BiLSTM(2 layers, bidir, H=512, E=1024) + FC(24) + CRF llh on MI355X.
// R3: rec restructured — fwd+bwd merged per WG (one exposed sync/step),
//     consumer h reads are PLAIN cached dwordx4 (write-once-read-once per
//     dispatch; disjoint hx per layer), single atomic counter per (dir,step).

typedef __bf16 bf16;
typedef _Float16 f16;
typedef __bf16 bf16x8 __attribute__((ext_vector_type(8)));
typedef __bf16 bf16x4 __attribute__((ext_vector_type(4)));
typedef _Float16 f16x4 __attribute__((ext_vector_type(4)));
typedef float f32x4 __attribute__((ext_vector_type(4)));
typedef unsigned int u32;
typedef unsigned long long u64;

#define TT 512
#define BB 32
#define HH 512
#define CC_ 24
#define MROWS 16384   // T*B
#define KDIM 1024     // E == 2H
#define NGATE 2048    // 4H

__device__ __forceinline__ f32x4 mfma16(bf16x8 a, bf16x8 b, f32x4 c) {
  return __builtin_amdgcn_mfma_f32_16x16x32_bf16(a, b, c, 0, 0, 0);
}
__device__ __forceinline__ float sigmoidf_(float x) { return 1.f / (1.f + __expf(-x)); }
__device__ __forceinline__ float tanhf_(float x) {
  float e = __expf(2.f * x);
  return 1.f - 2.f / (e + 1.f);
}

// ---------------- weight conversion fp32 -> bf16 ----------------
__global__ __launch_bounds__(256) void convert_w_k(
    const float* __restrict__ wih, const float* __restrict__ whh, const float* __restrict__ fcw,
    bf16* __restrict__ wihb, bf16* __restrict__ whhb, bf16* __restrict__ fcwb) {
  const int n1 = (2 * 2 * NGATE * KDIM) / 4;
  const int n2 = (2 * 2 * NGATE * HH) / 4;
  const int n3 = (32 * KDIM) / 4;
  int stride = gridDim.x * blockDim.x;
  for (int i = blockIdx.x * blockDim.x + threadIdx.x; i < n1 + n2 + n3; i += stride) {
    float4 v;
    bf16* dst;
    if (i < n1) {
      v = ((const float4*)wih)[i];
      dst = wihb + (size_t)i * 4;
    } else if (i < n1 + n2) {
      int j = i - n1;
      v = ((const float4*)whh)[j];
      dst = whhb + (size_t)j * 4;
    } else {
      int j = i - n1 - n2;
      if ((j >> 8) < CC_) v = ((const float4*)fcw)[j];
      else                v = make_float4(0.f, 0.f, 0.f, 0.f);
      dst = fcwb + (size_t)j * 4;
    }
    bf16x4 o; o[0] = (bf16)v.x; o[1] = (bf16)v.y; o[2] = (bf16)v.z; o[3] = (bf16)v.w;
    *(bf16x4*)dst = o;
  }
}

// ---------------- embedding gather -> xt[t*32+b][1024] bf16 ----------------
__global__ __launch_bounds__(64) void embed_k(const int* __restrict__ x,
                                              const float* __restrict__ emb,
                                              bf16* __restrict__ xt) {
  int row = blockIdx.x;
  int t = row >> 5, b = row & 31;
  int tok = x[b * TT + t];
  const float4* src = (const float4*)(emb + (size_t)tok * KDIM);
  bf16* dst = xt + (size_t)row * KDIM;
  int i = threadIdx.x;
#pragma unroll
  for (int c = 0; c < 4; ++c) {
    float4 v = src[i + 64 * c];
    bf16x4 o; o[0] = (bf16)v.x; o[1] = (bf16)v.y; o[2] = (bf16)v.z; o[3] = (bf16)v.w;
    *(bf16x4*)(dst + (size_t)(i + 64 * c) * 4) = o;
  }
}

// ---------------- input GEMM -> Gin fp16, per-WG layout ----------------
// Gh[dir][wg(64)][row(16384)][jj(8)*4+gate(4)]
__global__ __launch_bounds__(256, 2) void gemm_in_k(
    const bf16* __restrict__ A, const bf16* __restrict__ W,
    const float* __restrict__ bih, const float* __restrict__ bhh,
    f16* __restrict__ Gh) {
  __shared__ bf16 As[128 * 72];
  __shared__ bf16 Ws[128 * 72];
  int dir = blockIdx.z;
  const bf16* Wd = W + (size_t)dir * NGATE * KDIM;
  const float* bi = bih + dir * NGATE;
  const float* bh = bhh + dir * NGATE;
  f16* G = Gh + (size_t)dir * 64 * MROWS * 32;
  int m0 = blockIdx.y * 128;
  int n0 = blockIdx.x * 128;
  int tid = threadIdx.x;
  int lane = tid & 63, wave = tid >> 6;
  int wm = wave >> 1, wn = wave & 1;
  int cn = lane & 15, quad = lane >> 4;

  f32x4 zz = {0.f, 0.f, 0.f, 0.f};
  f32x4 acc[4][4];
#pragma unroll
  for (int a = 0; a < 4; ++a)
#pragma unroll
    for (int b = 0; b < 4; ++b) acc[a][b] = zz;

  for (int k0 = 0; k0 < KDIM; k0 += 64) {
    __syncthreads();
#pragma unroll
    for (int j = 0; j < 4; ++j) {
      int cch = tid + 256 * j;
      int row = cch >> 3, kq = cch & 7;
      *(bf16x8*)&As[row * 72 + kq * 8] =
          *(const bf16x8*)&A[(size_t)(m0 + row) * KDIM + k0 + kq * 8];
      *(bf16x8*)&Ws[row * 72 + kq * 8] =
          *(const bf16x8*)&Wd[(size_t)(n0 + row) * KDIM + k0 + kq * 8];
    }
    __syncthreads();
#pragma unroll
    for (int kc = 0; kc < 2; ++kc) {
      bf16x8 af[4], bw[4];
#pragma unroll
      for (int mt = 0; mt < 4; ++mt)
        af[mt] = *(const bf16x8*)&As[(wm * 64 + mt * 16 + cn) * 72 + kc * 32 + quad * 8];
#pragma unroll
      for (int nt = 0; nt < 4; ++nt)
        bw[nt] = *(const bf16x8*)&Ws[(wn * 64 + nt * 16 + cn) * 72 + kc * 32 + quad * 8];
#pragma unroll
      for (int mt = 0; mt < 4; ++mt)
#pragma unroll
        for (int nt = 0; nt < 4; ++nt)
          acc[mt][nt] = mfma16(af[mt], bw[nt], acc[mt][nt]);
    }
  }
#pragma unroll
  for (int nt = 0; nt < 4; ++nt) {
    int n = n0 + wn * 64 + nt * 16 + cn;
    float bias = bi[n] + bh[n];
    int col = n & 511, gate = n >> 9;
    size_t base = (size_t)(col >> 3) * MROWS * 32 + (size_t)(col & 7) * 4 + gate;
#pragma unroll
    for (int mt = 0; mt < 4; ++mt) {
#pragma unroll
      for (int r = 0; r < 4; ++r) {
        int row = m0 + wm * 64 + mt * 16 + quad * 4 + r;
        G[base + (size_t)row * 32] = (f16)(acc[mt][nt][r] + bias);
      }
    }
  }
}

// ---------------- persistent recurrence, fwd+bwd merged ----------------
// grid (64): each WG owns 8 h-cols (j0=wg*8) for BOTH directions.
// hx[dir][t]: 4096 u64 slots = [kc(64)][row(32)][half(2)] (16B per (kc,row)):
//   slot 16B (kc,row) = h[row][kc*8 .. kc*8+7]. WG wg produces kc==wg.
// Consumer reads are PLAIN dwordx4 (cached): every address written once
// (sc1, vmcnt-acked) before the step counter releases any reader.
__global__ __launch_bounds__(64) void rec2_k(
    const f16* __restrict__ Gin,     // [2][64][16384][32] fp16
    const bf16* __restrict__ Whh,    // [2][2048][512] bf16
    bf16* __restrict__ hbuf,         // [16384][1024] cached out (next layer)
    u64* __restrict__ hx,            // [2][512][4096] (this layer's region)
    u32* __restrict__ cnt) {         // [2][512] zeroed counters (this layer's)
  __builtin_amdgcn_fence(__ATOMIC_ACQUIRE, "agent");   // kill cross-launch stale lines
  int wg = blockIdx.x;
  int lane = threadIdx.x;
  int cn = lane & 15, quad = lane >> 4;
  int j0 = wg * 8;

  __shared__ bf16 Bl[2][32 * 520];   // per-dir Whh slice as B-frags
  __shared__ bf16 hS[2][32][8];      // per-dir transpose staging

#pragma unroll
  for (int d = 0; d < 2; ++d) {
    const bf16* Wd = Whh + (size_t)d * NGATE * HH;
    for (int c = lane; c < 32 * 64; c += 64) {
      int col = c >> 6, kc8 = c & 63;
      int nt = col >> 4, ccn = col & 15;
      int gate = nt * 2 + (ccn >> 3);
      int n = gate * HH + j0 + (ccn & 7);
      *(bf16x8*)&Bl[d][col * 520 + kc8 * 8] = *(const bf16x8*)&Wd[(size_t)n * HH + kc8 * 8];
    }
  }
  __syncthreads();

  float cst[2][2][4];
#pragma unroll
  for (int d = 0; d < 2; ++d)
#pragma unroll
    for (int mt = 0; mt < 2; ++mt)
#pragma unroll
      for (int r = 0; r < 4; ++r) cst[d][mt][r] = 0.f;

  bool active = cn < 8;
  int jj = cn & 7;
  f32x4 zz = {0.f, 0.f, 0.f, 0.f};
  int pb = lane >> 1, half = lane & 1;
  const f16* Gw[2] = { Gin + (size_t)wg * MROWS * 32,
                       Gin + (size_t)(64 + wg) * MROWS * 32 };
  u64* hxd[2] = { hx, hx + (size_t)TT * 4096 };

  for (int s = 0; s < TT; ++s) {
    int tt_[2]; tt_[0] = s; tt_[1] = TT - 1 - s;
    // prefetch both dirs' gate pre-activations (in flight across the polls)
    f16x4 gp[2][2][4];
    if (active) {
#pragma unroll
      for (int d = 0; d < 2; ++d)
#pragma unroll
        for (int mt = 0; mt < 2; ++mt)
#pragma unroll
          for (int r = 0; r < 4; ++r) {
            int b = mt * 16 + quad * 4 + r;
            gp[d][mt][r] = *(const f16x4*)&Gw[d][(size_t)(tt_[d] * BB + b) * 32 + jj * 4];
          }
    }
#pragma unroll
    for (int d = 0; d < 2; ++d) {
      int t = tt_[d];
      f32x4 acc[2][2];
      acc[0][0] = zz; acc[0][1] = zz; acc[1][0] = zz; acc[1][1] = zz;
      if (s > 0) {
        int tp = d ? (t + 1) : (t - 1);
        const u32* cp = &cnt[d * TT + s - 1];
        while (__hip_atomic_load(cp, __ATOMIC_RELAXED, __HIP_MEMORY_SCOPE_AGENT) < 64u)
          __builtin_amdgcn_s_sleep(1);
        asm volatile("" ::: "memory");   // loads below stay below the poll
        const uint4* hb16 = (const uint4*)(hxd[d] + (size_t)tp * 4096);
#pragma unroll 4
        for (int kk = 0; kk < 16; ++kk) {
          int kc = kk * 4 + quad;
          union { uint4 u; bf16x8 v; } a0, a1;
          a0.u = hb16[kc * 32 + cn];        // rows 0-15  (batch cn)
          a1.u = hb16[kc * 32 + cn + 16];   // rows 16-31
          bf16x8 b0 = *(const bf16x8*)&Bl[d][cn * 520 + kk * 32 + quad * 8];
          bf16x8 b1 = *(const bf16x8*)&Bl[d][(16 + cn) * 520 + kk * 32 + quad * 8];
          acc[0][0] = mfma16(a0.v, b0, acc[0][0]);
          acc[0][1] = mfma16(a0.v, b1, acc[0][1]);
          acc[1][0] = mfma16(a1.v, b0, acc[1][0]);
          acc[1][1] = mfma16(a1.v, b1, acc[1][1]);
        }
      }
#pragma unroll
      for (int mt = 0; mt < 2; ++mt) {
#pragma unroll
        for (int r = 0; r < 4; ++r) {
          float ip = acc[mt][0][r], gg = acc[mt][1][r];
          float fp = __shfl(ip, lane + 8);   // f-gate partial 8 lanes over
          float op = __shfl(gg, lane + 8);   // o-gate partial 8 lanes over
          if (active) {
            float xi = ip + (float)gp[d][mt][r][0];
            float xf = fp + (float)gp[d][mt][r][1];
            float xg = gg + (float)gp[d][mt][r][2];
            float xo = op + (float)gp[d][mt][r][3];
            float it = sigmoidf_(xi);
            float ft = sigmoidf_(xf);
            float gt = tanhf_(xg);
            float ot = sigmoidf_(xo);
            float cc = ft * cst[d][mt][r] + it * gt;
            cst[d][mt][r] = cc;
            hS[d][mt * 16 + quad * 4 + r][jj] = (bf16)(ot * tanhf_(cc));
          }
        }
      }
      __syncthreads();   // hS write -> read ordering (cross-lane)
      u64 pv = *(const u64*)&hS[d][pb][half * 4];
      __hip_atomic_store(&hxd[d][(size_t)t * 4096 + wg * 64 + lane], pv,
                         __ATOMIC_RELAXED, __HIP_MEMORY_SCOPE_AGENT);
      asm volatile("s_waitcnt vmcnt(0)" ::: "memory");   // data acked before release
      if (lane == 0)
        __hip_atomic_fetch_add(&cnt[d * TT + s], 1u, __ATOMIC_RELAXED,
                               __HIP_MEMORY_SCOPE_AGENT);
      *(u64*)&hbuf[(size_t)(t * BB + pb) * KDIM + d * HH + j0 + half * 4] = pv;
      __syncthreads();   // hS read (this step) before hS write (next step)
    }
  }
}

// ---------------- FC: logits[b][t][c] = h1 @ fcw^T + fcb ----------------
__global__ __launch_bounds__(64) void gemm_fc_k(
    const bf16* __restrict__ hbuf,
    const bf16* __restrict__ fcw,
    const float* __restrict__ fcb,
    float* __restrict__ outp) {
  int m0 = blockIdx.x * 16;
  int lane = threadIdx.x;
  int cn = lane & 15, quad = lane >> 4;
  f32x4 acc0 = {0.f, 0.f, 0.f, 0.f}, acc1 = {0.f, 0.f, 0.f, 0.f};
  for (int k0 = 0; k0 < KDIM; k0 += 32) {
    bf16x8 a  = *(const bf16x8*)&hbuf[(size_t)(m0 + cn) * KDIM + k0 + quad * 8];
    bf16x8 b0 = *(const bf16x8*)&fcw[(size_t)cn * KDIM + k0 + quad * 8];
    bf16x8 b1 = *(const bf16x8*)&fcw[(size_t)(cn + 16) * KDIM + k0 + quad * 8];
    acc0 = mfma16(a, b0, acc0);
    acc1 = mfma16(a, b1, acc1);
  }
#pragma unroll
  for (int r = 0; r < 4; ++r) {
    int row = m0 + quad * 4 + r;
    int t = row >> 5, b = row & 31;
    float* o = outp + (size_t)b * (TT * CC_) + (size_t)t * CC_;
    o[cn] = acc0[r] + fcb[cn];
    int c1 = cn + 16;
    if (c1 < CC_) o[c1] = acc1[r] + fcb[c1];
  }
  if (blockIdx.x == 0 && lane == 0) outp[(size_t)BB * TT * CC_] = 0.f;
}

// ---------------- CRF: one WG per batch element ----------------
__global__ __launch_bounds__(64) void crf_k(
    const float* __restrict__ em,
    const int* __restrict__ labels,
    const float* __restrict__ start_, const float* __restrict__ end_,
    const float* __restrict__ trans, float* __restrict__ result) {
  int b = blockIdx.x;
  int j = threadIdx.x;
  bool act = j < CC_;
  int jc = act ? j : 0;
  float tcol[CC_];
#pragma unroll
  for (int i = 0; i < CC_; ++i) tcol[i] = trans[i * CC_ + jc];
  const float* emb_ = em + (size_t)b * (TT * CC_);
  float alpha = act ? (start_[jc] + emb_[jc]) : -1e30f;
  for (int t = 1; t < TT; ++t) {
    float m = -1e30f;
#pragma unroll
    for (int i = 0; i < CC_; ++i) {
      float ai = __shfl(alpha, i);
      m = fmaxf(m, ai + tcol[i]);
    }
    float ssum = 0.f;
#pragma unroll
    for (int i = 0; i < CC_; ++i) {
      float ai = __shfl(alpha, i);
      ssum += __expf(ai + tcol[i] - m);
    }
    float na = m + __logf(ssum) + emb_[(size_t)t * CC_ + jc];
    alpha = act ? na : -1e30f;
  }
  float v = act ? (alpha + end_[jc]) : -1e30f;
  float mm = v;
#pragma unroll
  for (int off = 32; off; off >>= 1) mm = fmaxf(mm, __shfl_xor(mm, off));
  float e = act ? __expf(v - mm) : 0.f;
#pragma unroll
  for (int off = 32; off; off >>= 1) e += __shfl_xor(e, off);
  float logZ = mm + __logf(e);
  float part = 0.f;
  for (int t = j; t < TT; t += 64) {
    int tag = labels[b * TT + t];
    part += emb_[(size_t)t * CC_ + tag];
    if (t < TT - 1) part += trans[tag * CC_ + labels[b * TT + t + 1]];
  }
#pragma unroll
  for (int off = 32; off; off >>= 1) part += __shfl_xor(part, off);
  if (j == 0) {
    float num = part + start_[labels[b * TT]] + end_[labels[b * TT + TT - 1]];
    atomicAdd(result, logZ - num);
  }
}

extern "C" void kernel_launch(void* const* d_in, const int* in_sizes, int n_in,
                              void* d_out, int out_size, void* d_ws, size_t ws_size,
                              hipStream_t stream) {
  const int*   x      = (const int*)d_in[0];
  const int*   labels = (const int*)d_in[1];
  const float* emb    = (const float*)d_in[2];
  const float* w_ih   = (const float*)d_in[3];
  const float* w_hh   = (const float*)d_in[4];
  const float* b_ih   = (const float*)d_in[5];
  const float* b_hh   = (const float*)d_in[6];
  const float* fc_w   = (const float*)d_in[7];
  const float* fc_b   = (const float*)d_in[8];
  const float* crf_s  = (const float*)d_in[9];
  const float* crf_e  = (const float*)d_in[10];
  const float* crf_t  = (const float*)d_in[11];
  float* out = (float*)d_out;
  (void)in_sizes; (void)n_in; (void)out_size; (void)ws_size;

  // workspace carve-up (~327 MB)
  char* ws = (char*)d_ws;
  bf16* xt    = (bf16*)ws;                         //  33,554,432 B
  bf16* h0    = (bf16*)(ws + 33554432);            //  33,554,432
  bf16* h1    = (bf16*)(ws + 67108864);            //  33,554,432
  bf16* wihb  = (bf16*)(ws + 100663296);           //  16,777,216
  bf16* whhb  = (bf16*)(ws + 117440512);           //   8,388,608
  bf16* fcwb  = (bf16*)(ws + 125829120);           //      65,536
  f16*  gin   = (f16*)(ws + 125894656);            // 134,217,728 (fp16)
  u64*  hx    = (u64*)(ws + 260112384);            //  67,108,864 (2 layers)
  u32*  cnt   = (u32*)(ws + 327221248);            //       8,192

  hipMemsetAsync(cnt, 0, 2 * 2 * TT * sizeof(u32), stream);
  convert_w_k<<<2048, 256, 0, stream>>>(w_ih, w_hh, fc_w, wihb, whhb, fcwb);
  embed_k<<<MROWS, 64, 0, stream>>>(x, emb, xt);

  // layer 0
  gemm_in_k<<<dim3(16, 128, 2), 256, 0, stream>>>(xt, wihb, b_ih, b_hh, gin);
  rec2_k<<<64, 64, 0, stream>>>(gin, whhb, h0, hx, cnt);
  // layer 1 (disjoint hx + cnt regions — no cross-dispatch reuse)
  gemm_in_k<<<dim3(16, 128, 2), 256, 0, stream>>>(
      h0, wihb + (size_t)2 * NGATE * KDIM, b_ih + 2 * NGATE, b_hh + 2 * NGATE, gin);
  rec2_k<<<64, 64, 0, stream>>>(gin, whhb + (size_t)2 * NGATE * HH, h1,
                                hx + (size_t)2 * TT * 4096, cnt + 2 * TT);

  gemm_fc_k<<<MROWS / 16, 64, 0, stream>>>(h1, fcwb, fc_b, out);
  crf_k<<<BB, 64, 0, stream>>>(out, labels, crf_s, crf_e, crf_t,
                               out + (size_t)BB * TT * CC_);
}

// Round 4
// 10004.947 us; speedup vs baseline: 1.3870x; 1.3870x over previous
//
#include <hip/hip_runtime.h>

// BiLSTM(2 layers, bidir, H=512, E=1024) + FC(24) + CRF llh on MI355X.
// R4 = R2 parallelism + R3 memory scheme:
//  - grid (64,2): one direction per WG (fwd/bwd chains run on separate CUs)
//  - consumer h reads: PLAIN cached dwordx4 from hx (write-once-read-once
//    per dispatch; disjoint hx per layer) — no uncached broadcast storm
//  - single release counter per (dir,step); producer: sc1 store -> vmcnt(0)
//    -> atomic_add; hbuf store after release (off the critical chain)

typedef __bf16 bf16;
typedef _Float16 f16;
typedef __bf16 bf16x8 __attribute__((ext_vector_type(8)));
typedef __bf16 bf16x4 __attribute__((ext_vector_type(4)));
typedef _Float16 f16x4 __attribute__((ext_vector_type(4)));
typedef float f32x4 __attribute__((ext_vector_type(4)));
typedef unsigned int u32;
typedef unsigned long long u64;

#define TT 512
#define BB 32
#define HH 512
#define CC_ 24
#define MROWS 16384   // T*B
#define KDIM 1024     // E == 2H
#define NGATE 2048    // 4H

__device__ __forceinline__ f32x4 mfma16(bf16x8 a, bf16x8 b, f32x4 c) {
  return __builtin_amdgcn_mfma_f32_16x16x32_bf16(a, b, c, 0, 0, 0);
}
__device__ __forceinline__ float sigmoidf_(float x) { return 1.f / (1.f + __expf(-x)); }
__device__ __forceinline__ float tanhf_(float x) {
  float e = __expf(2.f * x);
  return 1.f - 2.f / (e + 1.f);
}

// ---------------- weight conversion fp32 -> bf16 ----------------
__global__ __launch_bounds__(256) void convert_w_k(
    const float* __restrict__ wih, const float* __restrict__ whh, const float* __restrict__ fcw,
    bf16* __restrict__ wihb, bf16* __restrict__ whhb, bf16* __restrict__ fcwb) {
  const int n1 = (2 * 2 * NGATE * KDIM) / 4;
  const int n2 = (2 * 2 * NGATE * HH) / 4;
  const int n3 = (32 * KDIM) / 4;
  int stride = gridDim.x * blockDim.x;
  for (int i = blockIdx.x * blockDim.x + threadIdx.x; i < n1 + n2 + n3; i += stride) {
    float4 v;
    bf16* dst;
    if (i < n1) {
      v = ((const float4*)wih)[i];
      dst = wihb + (size_t)i * 4;
    } else if (i < n1 + n2) {
      int j = i - n1;
      v = ((const float4*)whh)[j];
      dst = whhb + (size_t)j * 4;
    } else {
      int j = i - n1 - n2;
      if ((j >> 8) < CC_) v = ((const float4*)fcw)[j];
      else                v = make_float4(0.f, 0.f, 0.f, 0.f);
      dst = fcwb + (size_t)j * 4;
    }
    bf16x4 o; o[0] = (bf16)v.x; o[1] = (bf16)v.y; o[2] = (bf16)v.z; o[3] = (bf16)v.w;
    *(bf16x4*)dst = o;
  }
}

// ---------------- embedding gather -> xt[t*32+b][1024] bf16 ----------------
__global__ __launch_bounds__(64) void embed_k(const int* __restrict__ x,
                                              const float* __restrict__ emb,
                                              bf16* __restrict__ xt) {
  int row = blockIdx.x;
  int t = row >> 5, b = row & 31;
  int tok = x[b * TT + t];
  const float4* src = (const float4*)(emb + (size_t)tok * KDIM);
  bf16* dst = xt + (size_t)row * KDIM;
  int i = threadIdx.x;
#pragma unroll
  for (int c = 0; c < 4; ++c) {
    float4 v = src[i + 64 * c];
    bf16x4 o; o[0] = (bf16)v.x; o[1] = (bf16)v.y; o[2] = (bf16)v.z; o[3] = (bf16)v.w;
    *(bf16x4*)(dst + (size_t)(i + 64 * c) * 4) = o;
  }
}

// ---------------- input GEMM -> Gin fp16, per-WG layout ----------------
// Gh[dir][wg(64)][row(16384)][jj(8)*4+gate(4)]
__global__ __launch_bounds__(256, 2) void gemm_in_k(
    const bf16* __restrict__ A, const bf16* __restrict__ W,
    const float* __restrict__ bih, const float* __restrict__ bhh,
    f16* __restrict__ Gh) {
  __shared__ bf16 As[128 * 72];
  __shared__ bf16 Ws[128 * 72];
  int dir = blockIdx.z;
  const bf16* Wd = W + (size_t)dir * NGATE * KDIM;
  const float* bi = bih + dir * NGATE;
  const float* bh = bhh + dir * NGATE;
  f16* G = Gh + (size_t)dir * 64 * MROWS * 32;
  int m0 = blockIdx.y * 128;
  int n0 = blockIdx.x * 128;
  int tid = threadIdx.x;
  int lane = tid & 63, wave = tid >> 6;
  int wm = wave >> 1, wn = wave & 1;
  int cn = lane & 15, quad = lane >> 4;

  f32x4 zz = {0.f, 0.f, 0.f, 0.f};
  f32x4 acc[4][4];
#pragma unroll
  for (int a = 0; a < 4; ++a)
#pragma unroll
    for (int b = 0; b < 4; ++b) acc[a][b] = zz;

  for (int k0 = 0; k0 < KDIM; k0 += 64) {
    __syncthreads();
#pragma unroll
    for (int j = 0; j < 4; ++j) {
      int cch = tid + 256 * j;
      int row = cch >> 3, kq = cch & 7;
      *(bf16x8*)&As[row * 72 + kq * 8] =
          *(const bf16x8*)&A[(size_t)(m0 + row) * KDIM + k0 + kq * 8];
      *(bf16x8*)&Ws[row * 72 + kq * 8] =
          *(const bf16x8*)&Wd[(size_t)(n0 + row) * KDIM + k0 + kq * 8];
    }
    __syncthreads();
#pragma unroll
    for (int kc = 0; kc < 2; ++kc) {
      bf16x8 af[4], bw[4];
#pragma unroll
      for (int mt = 0; mt < 4; ++mt)
        af[mt] = *(const bf16x8*)&As[(wm * 64 + mt * 16 + cn) * 72 + kc * 32 + quad * 8];
#pragma unroll
      for (int nt = 0; nt < 4; ++nt)
        bw[nt] = *(const bf16x8*)&Ws[(wn * 64 + nt * 16 + cn) * 72 + kc * 32 + quad * 8];
#pragma unroll
      for (int mt = 0; mt < 4; ++mt)
#pragma unroll
        for (int nt = 0; nt < 4; ++nt)
          acc[mt][nt] = mfma16(af[mt], bw[nt], acc[mt][nt]);
    }
  }
#pragma unroll
  for (int nt = 0; nt < 4; ++nt) {
    int n = n0 + wn * 64 + nt * 16 + cn;
    float bias = bi[n] + bh[n];
    int col = n & 511, gate = n >> 9;
    size_t base = (size_t)(col >> 3) * MROWS * 32 + (size_t)(col & 7) * 4 + gate;
#pragma unroll
    for (int mt = 0; mt < 4; ++mt) {
#pragma unroll
      for (int r = 0; r < 4; ++r) {
        int row = m0 + wm * 64 + mt * 16 + quad * 4 + r;
        G[base + (size_t)row * 32] = (f16)(acc[mt][nt][r] + bias);
      }
    }
  }
}

// ---------------- persistent recurrence, one dir per WG ----------------
// grid (64,2): WG owns 8 h-cols (j0=wg*8) for direction blockIdx.y.
// hx[dir][t]: 4096 u64 slots = [kc(64)][row(32)][half(2)]:
//   slot (kc,row,half) = h[row][kc*8 + half*4 .. +3]; WG wg produces kc==wg.
// Consumer reads PLAIN dwordx4 (cached): every address written once (sc1,
// vmcnt-acked) before cnt releases any reader; disjoint hx per layer.
__global__ __launch_bounds__(64) void rec3_k(
    const f16* __restrict__ Gin,     // [2][64][16384][32] fp16
    const bf16* __restrict__ Whh,    // [2][2048][512] bf16
    bf16* __restrict__ hbuf,         // [16384][1024] cached out (next layer)
    u64* __restrict__ hx,            // [2][512][4096] (this layer's region)
    u32* __restrict__ cnt) {         // [2][512] zeroed (this layer's region)
  __builtin_amdgcn_fence(__ATOMIC_ACQUIRE, "agent");   // kill cross-launch stale lines
  int wg = blockIdx.x;
  int d = blockIdx.y;
  int lane = threadIdx.x;
  int cn = lane & 15, quad = lane >> 4;
  int j0 = wg * 8;

  __shared__ bf16 Bl[32 * 520];   // Whh slice as B-frags (i,f | g,o)
  __shared__ bf16 hS[32][8];      // transpose staging

  {
    const bf16* Wd = Whh + (size_t)d * NGATE * HH;
    for (int c = lane; c < 32 * 64; c += 64) {
      int col = c >> 6, kc8 = c & 63;
      int nt = col >> 4, ccn = col & 15;
      int gate = nt * 2 + (ccn >> 3);
      int n = gate * HH + j0 + (ccn & 7);
      *(bf16x8*)&Bl[col * 520 + kc8 * 8] = *(const bf16x8*)&Wd[(size_t)n * HH + kc8 * 8];
    }
  }
  __syncthreads();

  float cst[2][4];
#pragma unroll
  for (int mt = 0; mt < 2; ++mt)
#pragma unroll
    for (int r = 0; r < 4; ++r) cst[mt][r] = 0.f;

  bool active = cn < 8;
  int jj = cn & 7;
  f32x4 zz = {0.f, 0.f, 0.f, 0.f};
  int pb = lane >> 1, half = lane & 1;
  const f16* Gw = Gin + ((size_t)d * 64 + wg) * MROWS * 32;
  u64* hxd = hx + (size_t)d * TT * 4096;
  u32* cl = cnt + (size_t)d * TT;

  for (int s = 0; s < TT; ++s) {
    int t = d ? (TT - 1 - s) : s;
    // prefetch this step's gate pre-activations (in flight across the poll)
    f16x4 gp[2][4];
    if (active) {
#pragma unroll
      for (int mt = 0; mt < 2; ++mt)
#pragma unroll
        for (int r = 0; r < 4; ++r) {
          int b = mt * 16 + quad * 4 + r;
          gp[mt][r] = *(const f16x4*)&Gw[(size_t)(t * BB + b) * 32 + jj * 4];
        }
    }
    f32x4 acc[2][2];
    acc[0][0] = zz; acc[0][1] = zz; acc[1][0] = zz; acc[1][1] = zz;
    if (s > 0) {
      int tp = d ? (t + 1) : (t - 1);
      const u32* cp = &cl[s - 1];
      while (__hip_atomic_load(cp, __ATOMIC_RELAXED, __HIP_MEMORY_SCOPE_AGENT) < 64u)
        __builtin_amdgcn_s_sleep(1);
      asm volatile("" ::: "memory");   // loads below stay below the poll
      const uint4* hb16 = (const uint4*)(hxd + (size_t)tp * 4096);
#pragma unroll 4
      for (int kk = 0; kk < 16; ++kk) {
        int kc = kk * 4 + quad;
        union { uint4 u; bf16x8 v; } a0, a1;
        a0.u = hb16[kc * 32 + cn];        // batch rows 0-15
        a1.u = hb16[kc * 32 + cn + 16];   // batch rows 16-31
        bf16x8 b0 = *(const bf16x8*)&Bl[cn * 520 + kk * 32 + quad * 8];
        bf16x8 b1 = *(const bf16x8*)&Bl[(16 + cn) * 520 + kk * 32 + quad * 8];
        acc[0][0] = mfma16(a0.v, b0, acc[0][0]);
        acc[0][1] = mfma16(a0.v, b1, acc[0][1]);
        acc[1][0] = mfma16(a1.v, b0, acc[1][0]);
        acc[1][1] = mfma16(a1.v, b1, acc[1][1]);
      }
    }
#pragma unroll
    for (int mt = 0; mt < 2; ++mt) {
#pragma unroll
      for (int r = 0; r < 4; ++r) {
        float ip = acc[mt][0][r], gg = acc[mt][1][r];
        float fp = __shfl(ip, lane + 8);   // f-gate partial 8 lanes over
        float op = __shfl(gg, lane + 8);   // o-gate partial 8 lanes over
        if (active) {
          float xi = ip + (float)gp[mt][r][0];
          float xf = fp + (float)gp[mt][r][1];
          float xg = gg + (float)gp[mt][r][2];
          float xo = op + (float)gp[mt][r][3];
          float it = sigmoidf_(xi);
          float ft = sigmoidf_(xf);
          float gt = tanhf_(xg);
          float ot = sigmoidf_(xo);
          float cc = ft * cst[mt][r] + it * gt;
          cst[mt][r] = cc;
          hS[mt * 16 + quad * 4 + r][jj] = (bf16)(ot * tanhf_(cc));
        }
      }
    }
    __syncthreads();   // hS write -> read ordering
    u64 pv = *(const u64*)&hS[pb][half * 4];
    __hip_atomic_store(&hxd[(size_t)t * 4096 + wg * 64 + lane], pv,
                       __ATOMIC_RELAXED, __HIP_MEMORY_SCOPE_AGENT);
    asm volatile("s_waitcnt vmcnt(0)" ::: "memory");   // data acked before release
    if (lane == 0)
      __hip_atomic_fetch_add(&cl[s], 1u, __ATOMIC_RELAXED, __HIP_MEMORY_SCOPE_AGENT);
    *(u64*)&hbuf[(size_t)(t * BB + pb) * KDIM + d * HH + j0 + half * 4] = pv;
    __syncthreads();   // hS read (this step) before hS write (next step)
  }
}

// ---------------- FC: logits[b][t][c] = h1 @ fcw^T + fcb ----------------
__global__ __launch_bounds__(64) void gemm_fc_k(
    const bf16* __restrict__ hbuf,
    const bf16* __restrict__ fcw,
    const float* __restrict__ fcb,
    float* __restrict__ outp) {
  int m0 = blockIdx.x * 16;
  int lane = threadIdx.x;
  int cn = lane & 15, quad = lane >> 4;
  f32x4 acc0 = {0.f, 0.f, 0.f, 0.f}, acc1 = {0.f, 0.f, 0.f, 0.f};
  for (int k0 = 0; k0 < KDIM; k0 += 32) {
    bf16x8 a  = *(const bf16x8*)&hbuf[(size_t)(m0 + cn) * KDIM + k0 + quad * 8];
    bf16x8 b0 = *(const bf16x8*)&fcw[(size_t)cn * KDIM + k0 + quad * 8];
    bf16x8 b1 = *(const bf16x8*)&fcw[(size_t)(cn + 16) * KDIM + k0 + quad * 8];
    acc0 = mfma16(a, b0, acc0);
    acc1 = mfma16(a, b1, acc1);
  }
#pragma unroll
  for (int r = 0; r < 4; ++r) {
    int row = m0 + quad * 4 + r;
    int t = row >> 5, b = row & 31;
    float* o = outp + (size_t)b * (TT * CC_) + (size_t)t * CC_;
    o[cn] = acc0[r] + fcb[cn];
    int c1 = cn + 16;
    if (c1 < CC_) o[c1] = acc1[r] + fcb[c1];
  }
  if (blockIdx.x == 0 && lane == 0) outp[(size_t)BB * TT * CC_] = 0.f;
}

// ---------------- CRF: one WG per batch element ----------------
__global__ __launch_bounds__(64) void crf_k(
    const float* __restrict__ em,
    const int* __restrict__ labels,
    const float* __restrict__ start_, const float* __restrict__ end_,
    const float* __restrict__ trans, float* __restrict__ result) {
  int b = blockIdx.x;
  int j = threadIdx.x;
  bool act = j < CC_;
  int jc = act ? j : 0;
  float tcol[CC_];
#pragma unroll
  for (int i = 0; i < CC_; ++i) tcol[i] = trans[i * CC_ + jc];
  const float* emb_ = em + (size_t)b * (TT * CC_);
  float alpha = act ? (start_[jc] + emb_[jc]) : -1e30f;
  for (int t = 1; t < TT; ++t) {
    float m = -1e30f;
#pragma unroll
    for (int i = 0; i < CC_; ++i) {
      float ai = __shfl(alpha, i);
      m = fmaxf(m, ai + tcol[i]);
    }
    float ssum = 0.f;
#pragma unroll
    for (int i = 0; i < CC_; ++i) {
      float ai = __shfl(alpha, i);
      ssum += __expf(ai + tcol[i] - m);
    }
    float na = m + __logf(ssum) + emb_[(size_t)t * CC_ + jc];
    alpha = act ? na : -1e30f;
  }
  float v = act ? (alpha + end_[jc]) : -1e30f;
  float mm = v;
#pragma unroll
  for (int off = 32; off; off >>= 1) mm = fmaxf(mm, __shfl_xor(mm, off));
  float e = act ? __expf(v - mm) : 0.f;
#pragma unroll
  for (int off = 32; off; off >>= 1) e += __shfl_xor(e, off);
  float logZ = mm + __logf(e);
  float part = 0.f;
  for (int t = j; t < TT; t += 64) {
    int tag = labels[b * TT + t];
    part += emb_[(size_t)t * CC_ + tag];
    if (t < TT - 1) part += trans[tag * CC_ + labels[b * TT + t + 1]];
  }
#pragma unroll
  for (int off = 32; off; off >>= 1) part += __shfl_xor(part, off);
  if (j == 0) {
    float num = part + start_[labels[b * TT]] + end_[labels[b * TT + TT - 1]];
    atomicAdd(result, logZ - num);
  }
}

extern "C" void kernel_launch(void* const* d_in, const int* in_sizes, int n_in,
                              void* d_out, int out_size, void* d_ws, size_t ws_size,
                              hipStream_t stream) {
  const int*   x      = (const int*)d_in[0];
  const int*   labels = (const int*)d_in[1];
  const float* emb    = (const float*)d_in[2];
  const float* w_ih   = (const float*)d_in[3];
  const float* w_hh   = (const float*)d_in[4];
  const float* b_ih   = (const float*)d_in[5];
  const float* b_hh   = (const float*)d_in[6];
  const float* fc_w   = (const float*)d_in[7];
  const float* fc_b   = (const float*)d_in[8];
  const float* crf_s  = (const float*)d_in[9];
  const float* crf_e  = (const float*)d_in[10];
  const float* crf_t  = (const float*)d_in[11];
  float* out = (float*)d_out;
  (void)in_sizes; (void)n_in; (void)out_size; (void)ws_size;

  // workspace carve-up (~327 MB)
  char* ws = (char*)d_ws;
  bf16* xt    = (bf16*)ws;                         //  33,554,432 B
  bf16* h0    = (bf16*)(ws + 33554432);            //  33,554,432
  bf16* h1    = (bf16*)(ws + 67108864);            //  33,554,432
  bf16* wihb  = (bf16*)(ws + 100663296);           //  16,777,216
  bf16* whhb  = (bf16*)(ws + 117440512);           //   8,388,608
  bf16* fcwb  = (bf16*)(ws + 125829120);           //      65,536
  f16*  gin   = (f16*)(ws + 125894656);            // 134,217,728 (fp16)
  u64*  hx    = (u64*)(ws + 260112384);            //  67,108,864 (2 layers)
  u32*  cnt   = (u32*)(ws + 327221248);            //       8,192

  hipMemsetAsync(cnt, 0, 2 * 2 * TT * sizeof(u32), stream);
  convert_w_k<<<2048, 256, 0, stream>>>(w_ih, w_hh, fc_w, wihb, whhb, fcwb);
  embed_k<<<MROWS, 64, 0, stream>>>(x, emb, xt);

  // layer 0
  gemm_in_k<<<dim3(16, 128, 2), 256, 0, stream>>>(xt, wihb, b_ih, b_hh, gin);
  rec3_k<<<dim3(64, 2), 64, 0, stream>>>(gin, whhb, h0, hx, cnt);
  // layer 1 (disjoint hx + cnt regions — no cross-dispatch reuse)
  gemm_in_k<<<dim3(16, 128, 2), 256, 0, stream>>>(
      h0, wihb + (size_t)2 * NGATE * KDIM, b_ih + 2 * NGATE, b_hh + 2 * NGATE, gin);
  rec3_k<<<dim3(64, 2), 64, 0, stream>>>(gin, whhb + (size_t)2 * NGATE * HH, h1,
                                         hx + (size_t)2 * TT * 4096, cnt + 2 * TT);

  gemm_fc_k<<<MROWS / 16, 64, 0, stream>>>(h1, fcwb, fc_b, out);
  crf_k<<<BB, 64, 0, stream>>>(out, labels, crf_s, crf_e, crf_t,
                               out + (size_t)BB * TT * CC_);
}